// Round 1
// baseline (826.640 us; speedup 1.0000x reference)
//
#include <hip/hip_runtime.h>

#define N_NODES 100000
#define N_EDGES 1600000
#define D 32
#define ED 8
#define NEG_SLOPE 0.01f

// One thread per (edge, dim). 32 consecutive lanes = one edge.
__global__ __launch_bounds__(256) void gine_edge_kernel(
    const float* __restrict__ x,
    const float* __restrict__ edge_attr,
    const float* __restrict__ We,   // [8][32] this layer
    const float* __restrict__ be,   // [32]
    const int*   __restrict__ src,
    const int*   __restrict__ dst,
    float*       __restrict__ agg)
{
    __shared__ float We_s[ED * D];
    __shared__ float be_s[D];
    int t = threadIdx.x;
    if (t < ED * D) We_s[t] = We[t];
    if (t < D)      be_s[t] = be[t];
    __syncthreads();

    long gtid = (long)blockIdx.x * blockDim.x + t;
    int e = (int)(gtid >> 5);
    int d = (int)(gtid & 31);
    if (e >= N_EDGES) return;

    int s  = src[e];   // broadcast load across the 32-lane group
    int dn = dst[e];

    float acc = be_s[d];
#pragma unroll
    for (int k = 0; k < ED; ++k)
        acc += edge_attr[(long)e * ED + k] * We_s[k * D + d];

    float m = x[(long)s * D + d] + acc;   // coalesced 128B gather
    m = fmaxf(m, 0.0f);
    atomicAdd(&agg[(long)dn * D + d], m); // coalesced 128B scatter-add
}

// One thread per (node, dim). 32 lanes = one node; matmul via shfl.
__global__ __launch_bounds__(256) void gine_node_kernel(
    float*       __restrict__ x,     // updated in place
    const float* __restrict__ agg,
    const float* __restrict__ W,     // [32][32] this layer
    const float* __restrict__ b)     // [32]
{
    __shared__ float W_s[D * D];
    __shared__ float b_s[D];
    int t = threadIdx.x;
    for (int i = t; i < D * D; i += 256) W_s[i] = W[i];
    if (t < D) b_s[t] = b[t];
    __syncthreads();

    long gtid = (long)blockIdx.x * blockDim.x + t;
    int n = (int)(gtid >> 5);
    int d = (int)(gtid & 31);
    if (n >= N_NODES) return;

    float h = x[(long)n * D + d] + agg[(long)n * D + d];

    float acc = b_s[d];
#pragma unroll
    for (int k = 0; k < D; ++k) {
        float hk = __shfl(h, k, D);        // h[k] from lane k (width 32)
        acc += hk * W_s[k * D + d];        // bank-conflict-free / broadcast
    }
    float out = acc > 0.0f ? acc : NEG_SLOPE * acc;
    x[(long)n * D + d] = out;
}

extern "C" void kernel_launch(void* const* d_in, const int* in_sizes, int n_in,
                              void* d_out, int out_size, void* d_ws, size_t ws_size,
                              hipStream_t stream) {
    const float* x_in      = (const float*)d_in[0];
    const float* edge_attr = (const float*)d_in[1];
    const float* W         = (const float*)d_in[2];  // [3][32][32]
    const float* b         = (const float*)d_in[3];  // [3][32]
    const float* We        = (const float*)d_in[4];  // [3][8][32]
    const float* be        = (const float*)d_in[5];  // [3][32]
    const int*   ei        = (const int*)d_in[6];    // [2][E]
    const int* src = ei;
    const int* dst = ei + N_EDGES;

    float* x   = (float*)d_out;                      // live node features
    float* agg = (float*)d_ws;                       // N*D fp32 scratch

    size_t xbytes = (size_t)N_NODES * D * sizeof(float);
    hipMemcpyAsync(x, x_in, xbytes, hipMemcpyDeviceToDevice, stream);

    dim3 eblk(256), egrid(((long)N_EDGES * D + 255) / 256);
    dim3 nblk(256), ngrid(((long)N_NODES * D + 255) / 256);

    for (int l = 0; l < 3; ++l) {
        hipMemsetAsync(agg, 0, xbytes, stream);
        gine_edge_kernel<<<egrid, eblk, 0, stream>>>(
            x, edge_attr, We + (size_t)l * ED * D, be + (size_t)l * D, src, dst, agg);
        gine_node_kernel<<<ngrid, nblk, 0, stream>>>(
            x, agg, W + (size_t)l * D * D, b + (size_t)l * D);
    }
}

// Round 2
// 820.593 us; speedup vs baseline: 1.0074x; 1.0074x over previous
//
#include <hip/hip_runtime.h>

#define N_NODES 100000
#define N_EDGES 1600000
#define D 32
#define ED 8
#define NEG_SLOPE 0.01f

// ---------------- CSR build ----------------

__global__ __launch_bounds__(256) void hist_kernel(
    const int* __restrict__ dst, int* __restrict__ deg)
{
    int e = blockIdx.x * 256 + threadIdx.x;
    if (e < N_EDGES) atomicAdd(&deg[dst[e]], 1);
}

// One block of 1024 threads: exclusive scan of deg[N] (stored in row_ptr[0..N-1])
// in place -> row_ptr, and copy start cursors into offs.
__global__ __launch_bounds__(1024) void scan_kernel(
    int* __restrict__ row_ptr, int* __restrict__ offs)
{
    __shared__ int sdata[1024];
    const int t = threadIdx.x;
    const int CH = (N_NODES + 1023) / 1024;  // 98
    int beg = t * CH, end = min(N_NODES, beg + CH);

    int partial = 0;
    for (int i = beg; i < end; ++i) partial += row_ptr[i];

    sdata[t] = partial;
    __syncthreads();
    for (int off = 1; off < 1024; off <<= 1) {
        int v = (t >= off) ? sdata[t - off] : 0;
        __syncthreads();
        sdata[t] += v;
        __syncthreads();
    }
    int run = sdata[t] - partial;  // exclusive prefix of this chunk
    for (int i = beg; i < end; ++i) {
        int dg = row_ptr[i];
        row_ptr[i] = run;
        offs[i] = run;
        run += dg;
    }
    if (t == 1023) row_ptr[N_NODES] = sdata[1023];
}

__global__ __launch_bounds__(256) void scatter_kernel(
    const int*   __restrict__ src,
    const int*   __restrict__ dst,
    const float* __restrict__ edge_attr,
    int*         __restrict__ offs,
    int*         __restrict__ src_sorted,
    float*       __restrict__ ea_sorted)
{
    int e = blockIdx.x * 256 + threadIdx.x;
    if (e >= N_EDGES) return;
    int dn = dst[e];
    int pos = atomicAdd(&offs[dn], 1);
    src_sorted[pos] = src[e];
    const float4* ea4 = (const float4*)edge_attr;
    float4* es4 = (float4*)ea_sorted;
    es4[(long)pos * 2]     = ea4[(long)e * 2];
    es4[(long)pos * 2 + 1] = ea4[(long)e * 2 + 1];
}

// ---------------- fused GINE layer ----------------
// One 32-lane group per node: register-accumulated message sum, then shfl matmul.
__global__ __launch_bounds__(256) void gine_fused_kernel(
    const float* __restrict__ x_in,
    float*       __restrict__ x_out,
    const int*   __restrict__ row_ptr,
    const int*   __restrict__ src_sorted,
    const float* __restrict__ ea_sorted,
    const float* __restrict__ W,    // [32][32]
    const float* __restrict__ b,    // [32]
    const float* __restrict__ We,   // [8][32]
    const float* __restrict__ be)   // [32]
{
    __shared__ float W_s[D * D];
    __shared__ float We_s[ED * D];
    __shared__ float b_s[D];
    __shared__ float be_s[D];
    const int t = threadIdx.x;
    for (int i = t; i < D * D; i += 256) W_s[i] = W[i];
    if (t < ED * D) We_s[t] = We[t];
    if (t < D) { b_s[t] = b[t]; be_s[t] = be[t]; }
    __syncthreads();

    int group = blockIdx.x * 8 + (t >> 5);
    int d = t & 31;
    if (group >= N_NODES) return;
    const int n = group;

    int row = row_ptr[n];
    int rend = row_ptr[n + 1];

    float acc = 0.0f;
    // one-edge lookahead prefetch
    int s_next = 0; float ea_next = 0.0f;
    if (row < rend) {
        s_next  = src_sorted[row];
        ea_next = ea_sorted[(long)row * ED + (d & 7)];
    }
    for (int pos = row; pos < rend; ++pos) {
        int s = s_next; float ea = ea_next;
        if (pos + 1 < rend) {
            s_next  = src_sorted[pos + 1];
            ea_next = ea_sorted[(long)(pos + 1) * ED + (d & 7)];
        }
        float xv = x_in[(long)s * D + d];  // 128B gather, issued early
        float e = be_s[d];
#pragma unroll
        for (int k = 0; k < ED; ++k)
            e += __shfl(ea, k, 32) * We_s[k * D + d];
        acc += fmaxf(xv + e, 0.0f);
    }

    float h = x_in[(long)n * D + d] + acc;
    float o = b_s[d];
#pragma unroll
    for (int k = 0; k < D; ++k)
        o += __shfl(h, k, 32) * W_s[k * D + d];
    o = o > 0.0f ? o : NEG_SLOPE * o;
    x_out[(long)n * D + d] = o;
}

// ---------------- round-1 fallback (atomics) ----------------
__global__ __launch_bounds__(256) void gine_edge_kernel(
    const float* __restrict__ x, const float* __restrict__ edge_attr,
    const float* __restrict__ We, const float* __restrict__ be,
    const int* __restrict__ src, const int* __restrict__ dst,
    float* __restrict__ agg)
{
    __shared__ float We_s[ED * D];
    __shared__ float be_s[D];
    int t = threadIdx.x;
    if (t < ED * D) We_s[t] = We[t];
    if (t < D) be_s[t] = be[t];
    __syncthreads();
    long gtid = (long)blockIdx.x * blockDim.x + t;
    int e = (int)(gtid >> 5), d = (int)(gtid & 31);
    if (e >= N_EDGES) return;
    int s = src[e], dn = dst[e];
    float acc = be_s[d];
#pragma unroll
    for (int k = 0; k < ED; ++k)
        acc += edge_attr[(long)e * ED + k] * We_s[k * D + d];
    float m = fmaxf(x[(long)s * D + d] + acc, 0.0f);
    atomicAdd(&agg[(long)dn * D + d], m);
}

__global__ __launch_bounds__(256) void gine_node_kernel(
    float* __restrict__ x, const float* __restrict__ agg,
    const float* __restrict__ W, const float* __restrict__ b)
{
    __shared__ float W_s[D * D];
    __shared__ float b_s[D];
    int t = threadIdx.x;
    for (int i = t; i < D * D; i += 256) W_s[i] = W[i];
    if (t < D) b_s[t] = b[t];
    __syncthreads();
    long gtid = (long)blockIdx.x * blockDim.x + t;
    int n = (int)(gtid >> 5), d = (int)(gtid & 31);
    if (n >= N_NODES) return;
    float h = x[(long)n * D + d] + agg[(long)n * D + d];
    float acc = b_s[d];
#pragma unroll
    for (int k = 0; k < D; ++k)
        acc += __shfl(h, k, D) * W_s[k * D + d];
    x[(long)n * D + d] = acc > 0.0f ? acc : NEG_SLOPE * acc;
}

// ---------------- launch ----------------

extern "C" void kernel_launch(void* const* d_in, const int* in_sizes, int n_in,
                              void* d_out, int out_size, void* d_ws, size_t ws_size,
                              hipStream_t stream) {
    const float* x_in      = (const float*)d_in[0];
    const float* edge_attr = (const float*)d_in[1];
    const float* W         = (const float*)d_in[2];
    const float* b         = (const float*)d_in[3];
    const float* We        = (const float*)d_in[4];
    const float* be        = (const float*)d_in[5];
    const int*   ei        = (const int*)d_in[6];
    const int* src = ei;
    const int* dst = ei + N_EDGES;

    const size_t xbytes = (size_t)N_NODES * D * sizeof(float);

    // ws layout (256B aligned regions)
    auto align = [](size_t v) { return (v + 255) & ~(size_t)255; };
    size_t off_wsx  = 0;
    size_t off_rp   = align(off_wsx + xbytes);                       // row_ptr (N+1)
    size_t off_offs = align(off_rp + (N_NODES + 1) * sizeof(int));   // offs (N)
    size_t off_srcs = align(off_offs + N_NODES * sizeof(int));       // src_sorted (E)
    size_t off_eas  = align(off_srcs + N_EDGES * sizeof(int));       // ea_sorted (E*8)
    size_t need     = off_eas + (size_t)N_EDGES * ED * sizeof(float);

    if (ws_size >= need) {
        char* ws = (char*)d_ws;
        float* ws_x       = (float*)(ws + off_wsx);
        int*   row_ptr    = (int*)  (ws + off_rp);
        int*   offs       = (int*)  (ws + off_offs);
        int*   src_sorted = (int*)  (ws + off_srcs);
        float* ea_sorted  = (float*)(ws + off_eas);

        // CSR build (once; reused by all 3 layers)
        hipMemsetAsync(row_ptr, 0, (N_NODES + 1) * sizeof(int), stream);
        hist_kernel<<<(N_EDGES + 255) / 256, 256, 0, stream>>>(dst, row_ptr);
        scan_kernel<<<1, 1024, 0, stream>>>(row_ptr, offs);
        scatter_kernel<<<(N_EDGES + 255) / 256, 256, 0, stream>>>(
            src, dst, edge_attr, offs, src_sorted, ea_sorted);

        float* xout = (float*)d_out;
        dim3 blk(256), grid((N_NODES + 7) / 8);
        // layer 0: x_in -> d_out ; layer 1: d_out -> ws_x ; layer 2: ws_x -> d_out
        gine_fused_kernel<<<grid, blk, 0, stream>>>(x_in, xout, row_ptr, src_sorted,
            ea_sorted, W, b, We, be);
        gine_fused_kernel<<<grid, blk, 0, stream>>>(xout, ws_x, row_ptr, src_sorted,
            ea_sorted, W + D * D, b + D, We + ED * D, be + D);
        gine_fused_kernel<<<grid, blk, 0, stream>>>(ws_x, xout, row_ptr, src_sorted,
            ea_sorted, W + 2 * D * D, b + 2 * D, We + 2 * ED * D, be + 2 * D);
    } else {
        // fallback: round-1 atomic path
        float* x = (float*)d_out;
        float* agg = (float*)d_ws;
        hipMemcpyAsync(x, x_in, xbytes, hipMemcpyDeviceToDevice, stream);
        dim3 eblk(256), egrid(((long)N_EDGES * D + 255) / 256);
        dim3 nblk(256), ngrid(((long)N_NODES * D + 255) / 256);
        for (int l = 0; l < 3; ++l) {
            hipMemsetAsync(agg, 0, xbytes, stream);
            gine_edge_kernel<<<egrid, eblk, 0, stream>>>(
                x, edge_attr, We + (size_t)l * ED * D, be + (size_t)l * D, src, dst, agg);
            gine_node_kernel<<<ngrid, nblk, 0, stream>>>(
                x, agg, W + (size_t)l * D * D, b + (size_t)l * D);
        }
    }
}

// Round 3
// 607.085 us; speedup vs baseline: 1.3617x; 1.3517x over previous
//
#include <hip/hip_runtime.h>

#define N_NODES 100000
#define N_EDGES 1600000
#define D 32
#define ED 8
#define NEG_SLOPE 0.01f
#define NBLK ((N_NODES + 1023) / 1024)  // 98 scan blocks

// ---------------- CSR build ----------------

__global__ __launch_bounds__(256) void hist_kernel(
    const int* __restrict__ dst, int* __restrict__ deg)
{
    int e = blockIdx.x * 256 + threadIdx.x;
    if (e < N_EDGES) atomicAdd(&deg[dst[e]], 1);
}

// Phase 1: per-block reduce of deg -> bsums[NBLK]
__global__ __launch_bounds__(1024) void scan_phase1(
    const int* __restrict__ deg, int* __restrict__ bsums)
{
    __shared__ int s[1024];
    int t = threadIdx.x;
    int i = blockIdx.x * 1024 + t;
    s[t] = (i < N_NODES) ? deg[i] : 0;
    __syncthreads();
    for (int off = 512; off > 0; off >>= 1) {
        if (t < off) s[t] += s[t + off];
        __syncthreads();
    }
    if (t == 0) bsums[blockIdx.x] = s[0];
}

// Phase 2: exclusive scan of the NBLK block sums (single tiny block)
__global__ __launch_bounds__(128) void scan_phase2(int* __restrict__ bsums)
{
    __shared__ int s[128];
    int t = threadIdx.x;
    int v = (t < NBLK) ? bsums[t] : 0;
    s[t] = v;
    __syncthreads();
    for (int off = 1; off < 128; off <<= 1) {
        int u = (t >= off) ? s[t - off] : 0;
        __syncthreads();
        s[t] += u;
        __syncthreads();
    }
    if (t < NBLK) bsums[t] = s[t] - v;  // exclusive
}

// Phase 3: block-local inclusive scan + block offset -> row_ptr, offs
__global__ __launch_bounds__(1024) void scan_phase3(
    const int* __restrict__ deg, const int* __restrict__ bsums,
    int* __restrict__ row_ptr, int* __restrict__ offs)
{
    __shared__ int s[1024];
    int t = threadIdx.x;
    int i = blockIdx.x * 1024 + t;
    int v = (i < N_NODES) ? deg[i] : 0;
    s[t] = v;
    __syncthreads();
    for (int off = 1; off < 1024; off <<= 1) {
        int u = (t >= off) ? s[t - off] : 0;
        __syncthreads();
        s[t] += u;
        __syncthreads();
    }
    int excl = bsums[blockIdx.x] + s[t] - v;
    if (i < N_NODES) { row_ptr[i] = excl; offs[i] = excl; }
    else if (i == N_NODES) row_ptr[i] = excl;  // == N_EDGES
}

__global__ __launch_bounds__(256) void scatter_kernel(
    const int*   __restrict__ src,
    const int*   __restrict__ dst,
    const float* __restrict__ edge_attr,
    int*         __restrict__ offs,
    int*         __restrict__ src_sorted,
    float*       __restrict__ ea_sorted)
{
    int e = blockIdx.x * 256 + threadIdx.x;
    if (e >= N_EDGES) return;
    int dn = dst[e];
    int pos = atomicAdd(&offs[dn], 1);
    src_sorted[pos] = src[e];
    const float4* ea4 = (const float4*)edge_attr;
    float4* es4 = (float4*)ea_sorted;
    es4[(long)pos * 2]     = ea4[(long)e * 2];
    es4[(long)pos * 2 + 1] = ea4[(long)e * 2 + 1];
}

// ---------------- fused GINE layer ----------------
__global__ __launch_bounds__(256) void gine_fused_kernel(
    const float* __restrict__ x_in,
    float*       __restrict__ x_out,
    const int*   __restrict__ row_ptr,
    const int*   __restrict__ src_sorted,
    const float* __restrict__ ea_sorted,
    const float* __restrict__ W,    // [32][32]
    const float* __restrict__ b,    // [32]
    const float* __restrict__ We,   // [8][32]
    const float* __restrict__ be)   // [32]
{
    __shared__ float W_s[D * D];
    __shared__ float We_s[ED * D];
    __shared__ float b_s[D];
    __shared__ float be_s[D];
    const int t = threadIdx.x;
    for (int i = t; i < D * D; i += 256) W_s[i] = W[i];
    if (t < ED * D) We_s[t] = We[t];
    if (t < D) { b_s[t] = b[t]; be_s[t] = be[t]; }
    __syncthreads();

    int group = blockIdx.x * 8 + (t >> 5);
    int d = t & 31;
    if (group >= N_NODES) return;
    const int n = group;

    int row = row_ptr[n];
    int rend = row_ptr[n + 1];

    float acc = 0.0f;
    int s_next = 0; float ea_next = 0.0f;
    if (row < rend) {
        s_next  = src_sorted[row];
        ea_next = ea_sorted[(long)row * ED + (d & 7)];
    }
    for (int pos = row; pos < rend; ++pos) {
        int s = s_next; float ea = ea_next;
        if (pos + 1 < rend) {
            s_next  = src_sorted[pos + 1];
            ea_next = ea_sorted[(long)(pos + 1) * ED + (d & 7)];
        }
        float xv = x_in[(long)s * D + d];
        float e = be_s[d];
#pragma unroll
        for (int k = 0; k < ED; ++k)
            e += __shfl(ea, k, 32) * We_s[k * D + d];
        acc += fmaxf(xv + e, 0.0f);
    }

    float h = x_in[(long)n * D + d] + acc;
    float o = b_s[d];
#pragma unroll
    for (int k = 0; k < D; ++k)
        o += __shfl(h, k, 32) * W_s[k * D + d];
    o = o > 0.0f ? o : NEG_SLOPE * o;
    x_out[(long)n * D + d] = o;
}

// ---------------- round-1 fallback (atomics) ----------------
__global__ __launch_bounds__(256) void gine_edge_kernel(
    const float* __restrict__ x, const float* __restrict__ edge_attr,
    const float* __restrict__ We, const float* __restrict__ be,
    const int* __restrict__ src, const int* __restrict__ dst,
    float* __restrict__ agg)
{
    __shared__ float We_s[ED * D];
    __shared__ float be_s[D];
    int t = threadIdx.x;
    if (t < ED * D) We_s[t] = We[t];
    if (t < D) be_s[t] = be[t];
    __syncthreads();
    long gtid = (long)blockIdx.x * blockDim.x + t;
    int e = (int)(gtid >> 5), d = (int)(gtid & 31);
    if (e >= N_EDGES) return;
    int s = src[e], dn = dst[e];
    float acc = be_s[d];
#pragma unroll
    for (int k = 0; k < ED; ++k)
        acc += edge_attr[(long)e * ED + k] * We_s[k * D + d];
    float m = fmaxf(x[(long)s * D + d] + acc, 0.0f);
    atomicAdd(&agg[(long)dn * D + d], m);
}

__global__ __launch_bounds__(256) void gine_node_kernel(
    float* __restrict__ x, const float* __restrict__ agg,
    const float* __restrict__ W, const float* __restrict__ b)
{
    __shared__ float W_s[D * D];
    __shared__ float b_s[D];
    int t = threadIdx.x;
    for (int i = t; i < D * D; i += 256) W_s[i] = W[i];
    if (t < D) b_s[t] = b[t];
    __syncthreads();
    long gtid = (long)blockIdx.x * blockDim.x + t;
    int n = (int)(gtid >> 5), d = (int)(gtid & 31);
    if (n >= N_NODES) return;
    float h = x[(long)n * D + d] + agg[(long)n * D + d];
    float acc = b_s[d];
#pragma unroll
    for (int k = 0; k < D; ++k)
        acc += __shfl(h, k, D) * W_s[k * D + d];
    x[(long)n * D + d] = acc > 0.0f ? acc : NEG_SLOPE * acc;
}

// ---------------- launch ----------------

extern "C" void kernel_launch(void* const* d_in, const int* in_sizes, int n_in,
                              void* d_out, int out_size, void* d_ws, size_t ws_size,
                              hipStream_t stream) {
    const float* x_in      = (const float*)d_in[0];
    const float* edge_attr = (const float*)d_in[1];
    const float* W         = (const float*)d_in[2];
    const float* b         = (const float*)d_in[3];
    const float* We        = (const float*)d_in[4];
    const float* be        = (const float*)d_in[5];
    const int*   ei        = (const int*)d_in[6];
    const int* src = ei;
    const int* dst = ei + N_EDGES;

    const size_t xbytes = (size_t)N_NODES * D * sizeof(float);

    auto align = [](size_t v) { return (v + 255) & ~(size_t)255; };
    size_t off_wsx  = 0;
    size_t off_rp   = align(off_wsx + xbytes);                        // row_ptr (N+1)
    size_t off_offs = align(off_rp + (N_NODES + 1) * sizeof(int));    // offs (N)
    size_t off_deg  = align(off_offs + N_NODES * sizeof(int));        // deg (N)
    size_t off_bs   = align(off_deg + N_NODES * sizeof(int));         // bsums (128)
    size_t off_srcs = align(off_bs + 128 * sizeof(int));              // src_sorted (E)
    size_t off_eas  = align(off_srcs + (size_t)N_EDGES * sizeof(int));// ea_sorted (E*8)
    size_t need     = off_eas + (size_t)N_EDGES * ED * sizeof(float);

    if (ws_size >= need) {
        char* ws = (char*)d_ws;
        float* ws_x       = (float*)(ws + off_wsx);
        int*   row_ptr    = (int*)  (ws + off_rp);
        int*   offs       = (int*)  (ws + off_offs);
        int*   deg        = (int*)  (ws + off_deg);
        int*   bsums      = (int*)  (ws + off_bs);
        int*   src_sorted = (int*)  (ws + off_srcs);
        float* ea_sorted  = (float*)(ws + off_eas);

        hipMemsetAsync(deg, 0, N_NODES * sizeof(int), stream);
        hist_kernel<<<(N_EDGES + 255) / 256, 256, 0, stream>>>(dst, deg);
        scan_phase1<<<NBLK, 1024, 0, stream>>>(deg, bsums);
        scan_phase2<<<1, 128, 0, stream>>>(bsums);
        scan_phase3<<<NBLK, 1024, 0, stream>>>(deg, bsums, row_ptr, offs);
        scatter_kernel<<<(N_EDGES + 255) / 256, 256, 0, stream>>>(
            src, dst, edge_attr, offs, src_sorted, ea_sorted);

        float* xout = (float*)d_out;
        dim3 blk(256), grid((N_NODES + 7) / 8);
        gine_fused_kernel<<<grid, blk, 0, stream>>>(x_in, xout, row_ptr, src_sorted,
            ea_sorted, W, b, We, be);
        gine_fused_kernel<<<grid, blk, 0, stream>>>(xout, ws_x, row_ptr, src_sorted,
            ea_sorted, W + D * D, b + D, We + ED * D, be + D);
        gine_fused_kernel<<<grid, blk, 0, stream>>>(ws_x, xout, row_ptr, src_sorted,
            ea_sorted, W + 2 * D * D, b + 2 * D, We + 2 * ED * D, be + 2 * D);
    } else {
        float* x = (float*)d_out;
        float* agg = (float*)d_ws;
        hipMemcpyAsync(x, x_in, xbytes, hipMemcpyDeviceToDevice, stream);
        dim3 eblk(256), egrid(((long)N_EDGES * D + 255) / 256);
        dim3 nblk(256), ngrid(((long)N_NODES * D + 255) / 256);
        for (int l = 0; l < 3; ++l) {
            hipMemsetAsync(agg, 0, xbytes, stream);
            gine_edge_kernel<<<egrid, eblk, 0, stream>>>(
                x, edge_attr, We + (size_t)l * ED * D, be + (size_t)l * D, src, dst, agg);
            gine_node_kernel<<<ngrid, nblk, 0, stream>>>(
                x, agg, W + (size_t)l * D * D, b + (size_t)l * D);
        }
    }
}